// Round 16
// baseline (740.371 us; speedup 1.0000x reference)
//
#include <hip/hip_runtime.h>
#include <hip/hip_bf16.h>

#define HD 128
#define PROP 1000

typedef float f32x4 __attribute__((ext_vector_type(4)));
typedef short s16x8 __attribute__((ext_vector_type(8)));

__device__ __forceinline__ float silu_f(float v) { return v / (1.0f + __expf(-v)); }

__device__ __forceinline__ unsigned short f2bf(float f) {
    union { __hip_bfloat16 h; unsigned short u; } v;
    v.h = __float2bfloat16(f);
    return v.u;
}
__device__ __forceinline__ unsigned pk2(float a, float b) {
    union { __hip_bfloat162 h; unsigned u; } v;
    v.h = __float22bfloat162_rn(make_float2(a, b));
    return v.u;
}
__device__ __forceinline__ float bf2f_lo(unsigned u) { return __uint_as_float(u << 16); }
__device__ __forceinline__ float bf2f_hi(unsigned u) { return __uint_as_float(u & 0xffff0000u); }
__device__ __forceinline__ float4 ld4(const float* p) { return *(const float4*)p; }
__device__ __forceinline__ unsigned enc_max(float f) {
    unsigned u = __float_as_uint(f);
    return (u & 0x80000000u) ? ~u : (u | 0x80000000u);
}

// position permutation: m1/apre position p holds feature sigma(p); tau = sigma^-1
// sigma(p) = ((p>>2)&7)*16 + (p>>5)*4 + (p&3)

// ================= CSR build =================
__global__ void counti_kernel(const int* __restrict__ ei, int* __restrict__ cnt, int E) {
    int e = blockIdx.x * 256 + threadIdx.x;
    if (e < E) atomicAdd(&cnt[ei[e]], 1);
}

__global__ __launch_bounds__(1024) void scan_blk(
    const int* __restrict__ cnt, int* __restrict__ excl, int* __restrict__ bsum, int N)
{
    __shared__ int wsum[16], wexc[17];
    const int t = threadIdx.x, lane = t & 63, wid = t >> 6;
    const int gid = blockIdx.x * 1024 + t;
    int v = (gid < N) ? cnt[gid] : 0;
    int incl = v;
    #pragma unroll
    for (int d = 1; d < 64; d <<= 1) {
        int x = __shfl_up(incl, d, 64);
        if (lane >= d) incl += x;
    }
    if (lane == 63) wsum[wid] = incl;
    __syncthreads();
    if (t == 0) {
        int a = 0;
        #pragma unroll
        for (int w2 = 0; w2 < 16; ++w2) { wexc[w2] = a; a += wsum[w2]; }
        wexc[16] = a;
    }
    __syncthreads();
    if (gid < N) excl[gid] = wexc[wid] + incl - v;
    if (t == 0) bsum[blockIdx.x] = wexc[16];
}
__global__ __launch_bounds__(64) void scan_top(int* __restrict__ bsum, int nb) {
    const int lane = threadIdx.x;
    int v = (lane < nb) ? bsum[lane] : 0;
    int incl = v;
    #pragma unroll
    for (int d = 1; d < 64; d <<= 1) {
        int x = __shfl_up(incl, d, 64);
        if (lane >= d) incl += x;
    }
    if (lane < nb) bsum[lane] = incl - v;
}
__global__ void scan_add(const int* __restrict__ excl, const int* __restrict__ bsum,
                         int* __restrict__ rp, int* __restrict__ wp, int N, int E) {
    int gid = blockIdx.x * 256 + threadIdx.x;
    if (gid < N) {
        int r = excl[gid] + bsum[gid >> 10];
        rp[gid] = r; wp[gid] = r;
    }
    if (gid == 0) rp[N] = E;
}

__global__ void scatter_kernel(const int* __restrict__ ei, int* __restrict__ wp,
                               int* __restrict__ perm, int* __restrict__ rows_s,
                               int* __restrict__ cols_s, int E) {
    int e = blockIdx.x * 256 + threadIdx.x;
    if (e < E) {
        int r = ei[e];
        int p = atomicAdd(&wp[r], 1);
        perm[p] = e;
        rows_s[p] = r;
        cols_s[p] = ei[E + e];
    }
}

__global__ void eattr_perm_kernel(const float* __restrict__ eattr, const int* __restrict__ perm,
                                  unsigned short* __restrict__ eperm, int E) {
    int i = blockIdx.x * 256 + threadIdx.x;
    if (i >= E) return;
    const float* src = eattr + (size_t)perm[i] * 16;
    float4 a = ld4(src), b = ld4(src + 4), c = ld4(src + 8), d = ld4(src + 12);
    unsigned short* dst = eperm + (size_t)i * 16;
    *(uint4*)dst       = make_uint4(pk2(a.x, a.y), pk2(a.z, a.w), pk2(b.x, b.y), pk2(b.z, b.w));
    *(uint4*)(dst + 8) = make_uint4(pk2(c.x, c.y), pk2(c.z, c.w), pk2(d.x, d.y), pk2(d.z, d.w));
}

// ================= fused weight prep (single launch; also ginit) =================
__global__ void prep_all(
    const float* __restrict__ ew1, const float* __restrict__ ew2, const float* __restrict__ cw1,
    const float* __restrict__ nw1, const float* __restrict__ nw2,
    const float* __restrict__ emb_in_w, const float* __restrict__ emb_out_w,
    unsigned short* __restrict__ w1nc, unsigned short* __restrict__ wattr,
    unsigned short* __restrict__ wt2, unsigned short* __restrict__ cwt1,
    unsigned short* __restrict__ nw1t, unsigned short* __restrict__ nw2t,
    unsigned short* __restrict__ wembt, unsigned short* __restrict__ wot,
    unsigned* __restrict__ g_enc, int ng)
{
    int idx = blockIdx.x * 256 + threadIdx.x;
    if (idx < 131072) {   // w1nc [4][256][128]
        int k = idx & 127, o2 = (idx >> 7) & 255, l = idx >> 15;
        w1nc[idx] = f2bf(ew1[((size_t)l * 273 + k + ((o2 >> 7) << 7)) * 128 + (o2 & 127)]);
        return;
    }
    idx -= 131072;
    if (idx < 16384) {    // wattr [4][128][32]
        int k = idx & 31, o = (idx >> 5) & 127, l = idx >> 12;
        int ksrc = (k < 16) ? (257 + k) : (k == 16 ? 256 : -1);
        float v = (ksrc >= 0) ? ew1[((size_t)l * 273 + ksrc) * 128 + o] : 0.0f;
        wattr[idx] = f2bf(v);
        return;
    }
    idx -= 16384;
    if (idx < 65536) {    // wt2 sigma-permuted [4][128][128]
        int k = idx & 127, o = (idx >> 7) & 127, l = idx >> 14;
        int ks = ((k >> 2) & 7) * 16 + ((k >> 5) << 2) + (k & 3);
        wt2[idx] = f2bf(ew2[((size_t)l * 128 + ks) * 128 + o]);
        return;
    }
    idx -= 65536;
    if (idx < 65536) {    // cwt1 [4][128][128]
        int k = idx & 127, o = (idx >> 7) & 127, l = idx >> 14;
        cwt1[idx] = f2bf(cw1[((size_t)l * 128 + k) * 128 + o]);
        return;
    }
    idx -= 65536;
    if (idx < 131072) {   // nw1t [4][128][256]
        int k = idx % 256, o = (idx / 256) & 127, l = idx / (256 * 128);
        nw1t[idx] = f2bf(nw1[((size_t)l * 256 + k) * 128 + o]);
        return;
    }
    idx -= 131072;
    if (idx < 65536) {    // nw2t [4][128][128]
        int k = idx & 127, o = (idx >> 7) & 127, l = idx >> 14;
        nw2t[idx] = f2bf(nw2[((size_t)l * 128 + k) * 128 + o]);
        return;
    }
    idx -= 65536;
    if (idx < 8192) {     // wembt [128][64]
        int k = idx & 63, o = idx >> 6;
        wembt[idx] = f2bf(emb_in_w[(size_t)k * 128 + o]);
        return;
    }
    idx -= 8192;
    if (idx < 16384) {    // wot [128][128]
        int k = idx & 127, o = idx >> 7;
        wot[idx] = f2bf(emb_out_w[(size_t)k * 128 + o]);
        return;
    }
    idx -= 16384;
    if (idx < ng) g_enc[idx] = 0x007FFFFFu;
}

// ================= fused emb + layer-0 apre (128 thr = 2 waves x 16 nodes) =================
__global__ __launch_bounds__(128) void emb_pre_kernel(
    const float* __restrict__ x, const unsigned short* __restrict__ wembt,
    const float* __restrict__ bemb,
    const unsigned short* __restrict__ w1nc, const float* __restrict__ b1,
    float* __restrict__ h, unsigned short* __restrict__ apre, int N)
{
    __shared__ __align__(16) char s_xt[32 * 128];
    __shared__ __align__(16) char s_h[32 * 256];
    const int tid = threadIdx.x;
    const int lane = tid & 63, wid = tid >> 6;
    const int lr = lane & 15, kg = lane >> 4;
    const int n0 = blockIdx.x * 32 + wid * 16;
    {
        int n16 = lane >> 2, q = lane & 3;
        int nn = min(n0 + n16, N - 1);
        int sw2 = (n16 & 7) << 4;
        char* row = s_xt + (wid * 16 + n16) * 128;
        #pragma unroll
        for (int it = 0; it < 4; ++it) {
            float4 v = ld4(x + (size_t)nn * 64 + q * 16 + it * 4);
            *(uint2*)(row + ((q * 32 + it * 8) ^ sw2)) = make_uint2(pk2(v.x, v.y), pk2(v.z, v.w));
        }
    }
    const int nd = n0 + lr;
    const int sw = (lr & 7) << 4;
    f32x4 acc[8];
    #pragma unroll
    for (int mf = 0; mf < 8; ++mf) acc[mf] = (f32x4){0.f, 0.f, 0.f, 0.f};
    {
        const char* brow = s_xt + (wid * 16 + lr) * 128;
        for (int ks = 0; ks < 2; ++ks) {
            s16x8 b = *(const s16x8*)(brow + ((ks * 64 + kg * 16) ^ sw));
            #pragma unroll
            for (int mf = 0; mf < 8; ++mf) {
                s16x8 a = *(const s16x8*)(wembt + (size_t)(mf * 16 + lr) * 64 + ks * 32 + kg * 8);
                acc[mf] = __builtin_amdgcn_mfma_f32_16x16x32_bf16(a, b, acc[mf], 0, 0, 0);
            }
        }
    }
    char* hrow = s_h + (wid * 16 + lr) * 256;
    #pragma unroll
    for (int mf = 0; mf < 8; ++mf) {
        f32x4 bb = *(const f32x4*)(bemb + mf * 16 + kg * 4);
        float v0 = acc[mf][0] + bb[0];
        float v1 = acc[mf][1] + bb[1];
        float v2 = acc[mf][2] + bb[2];
        float v3 = acc[mf][3] + bb[3];
        if (nd < N) *(f32x4*)(h + (size_t)nd * HD + mf * 16 + kg * 4) = (f32x4){v0, v1, v2, v3};
        *(uint2*)(hrow + ((mf * 32 + kg * 8) ^ sw)) = make_uint2(pk2(v0, v1), pk2(v2, v3));
    }
    f32x4 acc2[16];
    #pragma unroll
    for (int mf = 0; mf < 16; ++mf) acc2[mf] = (f32x4){0.f, 0.f, 0.f, 0.f};
    for (int ks = 0; ks < 4; ++ks) {
        s16x8 b = *(const s16x8*)(hrow + ((ks * 64 + kg * 16) ^ sw));
        #pragma unroll
        for (int mf = 0; mf < 16; ++mf) {
            s16x8 a = *(const s16x8*)(w1nc + (size_t)(mf * 16 + lr) * 128 + ks * 32 + kg * 8);
            acc2[mf] = __builtin_amdgcn_mfma_f32_16x16x32_bf16(a, b, acc2[mf], 0, 0, 0);
        }
    }
    if (nd < N) {
        #pragma unroll
        for (int mf = 0; mf < 16; ++mf) {
            float b0 = 0.f, b1v = 0.f, b2v = 0.f, b3v = 0.f;
            if (mf < 8) {
                f32x4 bb = *(const f32x4*)(b1 + mf * 16 + kg * 4);
                b0 = bb[0]; b1v = bb[1]; b2v = bb[2]; b3v = bb[3];
            }
            int pos = ((mf >> 3) << 7) + kg * 32 + (mf & 7) * 4;
            *(uint2*)(apre + (size_t)nd * 256 + pos) =
                make_uint2(pk2(acc2[mf][0] + b0, acc2[mf][1] + b1v), pk2(acc2[mf][2] + b2v, acc2[mf][3] + b3v));
        }
    }
}

// ================= edge compute: 1 wave = 64 edges (4 tiles), shared A-frags =================
__global__ __launch_bounds__(64) void edge_compute_kernel(
    const float* __restrict__ pos, const unsigned short* __restrict__ apre,
    const unsigned short* __restrict__ eperm,
    const int* __restrict__ rows_s, const int* __restrict__ cols_s,
    const unsigned short* __restrict__ wattr,
    const unsigned short* __restrict__ wt2, const float* __restrict__ b2,
    const unsigned short* __restrict__ cwt1, const float* __restrict__ cb1,
    const float* __restrict__ cw2,
    unsigned short* __restrict__ medge, float* __restrict__ trans, int E)
{
    __shared__ __align__(16) char s_m[4][16 * 256];

    // bijective XCD swizzle (works for any grid size)
    int wg = blockIdx.x;
    {
        int nwg = gridDim.x;
        int q = nwg >> 3, rr = nwg & 7;
        int xcd = wg & 7, idx = wg >> 3;
        wg = (xcd < rr) ? (xcd * (q + 1) + idx) : (rr * (q + 1) + (xcd - rr) * q + idx);
    }
    const int lane = threadIdx.x;
    const int lr = lane & 15, kg = lane >> 4;
    const int i0 = wg * 64;

    int rT[4], cT[4];
    float dxT[4], dyT[4], dzT[4];
    #pragma unroll
    for (int t = 0; t < 4; ++t) {
        int ic = min(i0 + t * 16 + lr, E - 1);
        rT[t] = rows_s[ic];
        cT[t] = cols_s[ic];
        dxT[t] = pos[rT[t]*3+0] - pos[cT[t]*3+0];
        dyT[t] = pos[rT[t]*3+1] - pos[cT[t]*3+1];
        dzT[t] = pos[rT[t]*3+2] - pos[cT[t]*3+2];
    }

    union { s16x8 v; unsigned u[4]; } battr[4];
    #pragma unroll
    for (int t = 0; t < 4; ++t) {
        int ic = min(i0 + t * 16 + lr, E - 1);
        if (kg < 2) {
            battr[t].v = *(const s16x8*)(eperm + (size_t)ic * 16 + kg * 8);
        } else {
            float rad = dxT[t]*dxT[t] + dyT[t]*dyT[t] + dzT[t]*dzT[t];
            battr[t].u[0] = (kg == 2) ? pk2(rad, 0.f) : 0u;
            battr[t].u[1] = 0u; battr[t].u[2] = 0u; battr[t].u[3] = 0u;
        }
    }

    const int sw = (lr & 7) << 4;
    f32x4 acc[4][8];
    #pragma unroll
    for (int t = 0; t < 4; ++t)
        #pragma unroll
        for (int mf = 0; mf < 8; ++mf) acc[t][mf] = (f32x4){0,0,0,0};

    // GEMM1: shared wattr A-frag across 4 tiles
    #pragma unroll
    for (int mf = 0; mf < 8; ++mf) {
        s16x8 a = *(const s16x8*)(wattr + (size_t)(mf * 16 + lr) * 32 + kg * 8);
        #pragma unroll
        for (int t = 0; t < 4; ++t)
            acc[t][mf] = __builtin_amdgcn_mfma_f32_16x16x32_bf16(a, battr[t].v, acc[t][mf], 0, 0, 0);
    }
    // epilogue per tile: direct tau gathers + silu, tau store
    #pragma unroll
    for (int t = 0; t < 4; ++t) {
        char* mrow = s_m[t] + lr * 256;
        uint4 rgq[4], cgq[4];
        {
            const unsigned short* rb = apre + (size_t)rT[t] * 256 + kg * 32;
            const unsigned short* cb = apre + (size_t)cT[t] * 256 + 128 + kg * 32;
            #pragma unroll
            for (int q = 0; q < 4; ++q) {
                rgq[q] = *(const uint4*)(rb + q * 8);
                cgq[q] = *(const uint4*)(cb + q * 8);
            }
        }
        #pragma unroll
        for (int mf = 0; mf < 8; ++mf) {
            unsigned rlo = ((const unsigned*)&rgq[mf >> 1])[(mf & 1) * 2];
            unsigned rhi = ((const unsigned*)&rgq[mf >> 1])[(mf & 1) * 2 + 1];
            unsigned clo = ((const unsigned*)&cgq[mf >> 1])[(mf & 1) * 2];
            unsigned chi = ((const unsigned*)&cgq[mf >> 1])[(mf & 1) * 2 + 1];
            float v0 = silu_f(acc[t][mf][0] + bf2f_lo(rlo) + bf2f_lo(clo));
            float v1 = silu_f(acc[t][mf][1] + bf2f_hi(rlo) + bf2f_hi(clo));
            float v2 = silu_f(acc[t][mf][2] + bf2f_lo(rhi) + bf2f_lo(chi));
            float v3 = silu_f(acc[t][mf][3] + bf2f_hi(rhi) + bf2f_hi(chi));
            *(uint2*)(mrow + ((kg * 64 + mf * 8) ^ sw)) = make_uint2(pk2(v0, v1), pk2(v2, v3));
        }
    }

    // GEMM2: shared wt2 A-frags across 4 tiles
    #pragma unroll
    for (int t = 0; t < 4; ++t)
        #pragma unroll
        for (int mf = 0; mf < 8; ++mf) acc[t][mf] = (f32x4){0,0,0,0};
    for (int ks = 0; ks < 4; ++ks) {
        s16x8 bT[4];
        #pragma unroll
        for (int t = 0; t < 4; ++t)
            bT[t] = *(const s16x8*)(s_m[t] + lr * 256 + ((ks * 64 + kg * 16) ^ sw));
        #pragma unroll
        for (int mf = 0; mf < 8; ++mf) {
            s16x8 a = *(const s16x8*)(wt2 + (size_t)(mf * 16 + lr) * 128 + ks * 32 + kg * 8);
            #pragma unroll
            for (int t = 0; t < 4; ++t)
                acc[t][mf] = __builtin_amdgcn_mfma_f32_16x16x32_bf16(a, bT[t], acc[t][mf], 0, 0, 0);
        }
    }
    #pragma unroll
    for (int t = 0; t < 4; ++t) {
        char* mrow = s_m[t] + lr * 256;
        #pragma unroll
        for (int mf = 0; mf < 8; ++mf) {
            f32x4 bb = *(const f32x4*)(b2 + mf * 16 + kg * 4);
            float v0 = silu_f(acc[t][mf][0] + bb[0]);
            float v1 = silu_f(acc[t][mf][1] + bb[1]);
            float v2 = silu_f(acc[t][mf][2] + bb[2]);
            float v3 = silu_f(acc[t][mf][3] + bb[3]);
            *(uint2*)(mrow + ((mf * 32 + kg * 8) ^ sw)) = make_uint2(pk2(v0, v1), pk2(v2, v3));
        }
    }

    // GEMM3: shared cwt1 A-frags across 4 tiles
    #pragma unroll
    for (int t = 0; t < 4; ++t)
        #pragma unroll
        for (int mf = 0; mf < 8; ++mf) acc[t][mf] = (f32x4){0,0,0,0};
    for (int ks = 0; ks < 4; ++ks) {
        s16x8 bT[4];
        #pragma unroll
        for (int t = 0; t < 4; ++t)
            bT[t] = *(const s16x8*)(s_m[t] + lr * 256 + ((ks * 64 + kg * 16) ^ sw));
        #pragma unroll
        for (int mf = 0; mf < 8; ++mf) {
            s16x8 a = *(const s16x8*)(cwt1 + (size_t)(mf * 16 + lr) * 128 + ks * 32 + kg * 8);
            #pragma unroll
            for (int t = 0; t < 4; ++t)
                acc[t][mf] = __builtin_amdgcn_mfma_f32_16x16x32_bf16(a, bT[t], acc[t][mf], 0, 0, 0);
        }
    }

    // coalesced medge writes for all tiles
    {
        int e = lane >> 2, q = lane & 3;
        int sw2 = (e & 7) << 4;
        #pragma unroll
        for (int t = 0; t < 4; ++t) {
            int ie = i0 + t * 16 + e;
            if (ie < E) {
                const char* src = s_m[t] + e * 256;
                char* dst = (char*)(medge + (size_t)ie * HD);
                #pragma unroll
                for (int it = 0; it < 4; ++it) {
                    uint4 v = *(const uint4*)(src + ((it * 64 + q * 16) ^ sw2));
                    *(uint4*)(dst + it * 64 + q * 16) = v;
                }
            }
        }
    }

    // coord scalars for all tiles
    #pragma unroll
    for (int t = 0; t < 4; ++t) {
        float part = 0.f;
        #pragma unroll
        for (int mf = 0; mf < 8; ++mf) {
            f32x4 bb = *(const f32x4*)(cb1 + mf * 16 + kg * 4);
            f32x4 cw = *(const f32x4*)(cw2 + mf * 16 + kg * 4);
            part += silu_f(acc[t][mf][0] + bb[0]) * cw[0];
            part += silu_f(acc[t][mf][1] + bb[1]) * cw[1];
            part += silu_f(acc[t][mf][2] + bb[2]) * cw[2];
            part += silu_f(acc[t][mf][3] + bb[3]) * cw[3];
        }
        part += __shfl_xor(part, 16, 64);
        part += __shfl_xor(part, 32, 64);
        if (kg == 0) {
            int ie = i0 + t * 16 + lr;
            if (ie < E)
                *(float4*)(trans + (size_t)ie * 4) =
                    make_float4(dxT[t] * part, dyT[t] * part, dzT[t] * part, 0.f);
        }
    }
}

// ================= node model: 1 wave = 32 nodes (2 tiles), shared A-frags =================
__global__ __launch_bounds__(64) void node_fused_kernel(
    float* __restrict__ h, const unsigned short* __restrict__ medge,
    const float* __restrict__ trans, const int* __restrict__ rp,
    float* __restrict__ pos,
    const unsigned short* __restrict__ nw1t, const float* __restrict__ nb1,
    const unsigned short* __restrict__ nw2t, const float* __restrict__ nb2,
    const unsigned short* __restrict__ w1nc_next, const float* __restrict__ b1_next,
    unsigned short* __restrict__ apre, int N, int has_next)
{
    __shared__ __align__(16) char s_x[2][16 * 512];
    const int lane = threadIdx.x;
    const int lr = lane & 15, kg = lane >> 4;
    const int n0 = blockIdx.x * 32;
    #pragma unroll
    for (int t = 0; t < 2; ++t) {
        int n16 = lane >> 2, q = lane & 3;
        int nid = n0 + t * 16 + n16;
        int nn = min(nid, N - 1);
        int sw2 = (n16 & 7) << 4;
        char* row = s_x[t] + n16 * 512;
        #pragma unroll
        for (int it = 0; it < 8; ++it) {
            int c2 = q * 32 + it * 4;
            float4 v = ld4(h + (size_t)nn * HD + c2);
            *(uint2*)(row + ((c2 * 2) ^ sw2)) = make_uint2(pk2(v.x, v.y), pk2(v.z, v.w));
        }
        const int s = rp[nn], e2 = rp[nn + 1];
        float a[32];
        #pragma unroll
        for (int u = 0; u < 32; ++u) a[u] = 0.f;
        for (int j = s; j < e2; ++j) {
            const unsigned short* mp = medge + (size_t)j * HD + q * 32;
            #pragma unroll
            for (int v4 = 0; v4 < 4; ++v4) {
                uint4 w = *(const uint4*)(mp + v4 * 8);
                a[v4*8+0] += bf2f_lo(w.x); a[v4*8+1] += bf2f_hi(w.x);
                a[v4*8+2] += bf2f_lo(w.y); a[v4*8+3] += bf2f_hi(w.y);
                a[v4*8+4] += bf2f_lo(w.z); a[v4*8+5] += bf2f_hi(w.z);
                a[v4*8+6] += bf2f_lo(w.w); a[v4*8+7] += bf2f_hi(w.w);
            }
        }
        #pragma unroll
        for (int it2 = 0; it2 < 4; ++it2) {
            uint4 w = make_uint4(pk2(a[it2*8+0], a[it2*8+1]), pk2(a[it2*8+2], a[it2*8+3]),
                                 pk2(a[it2*8+4], a[it2*8+5]), pk2(a[it2*8+6], a[it2*8+7]));
            *(uint4*)(row + ((256 + q * 64 + it2 * 16) ^ sw2)) = w;
        }
        if (q < 3 && nid < N) {
            float pa = 0.f;
            for (int j = s; j < e2; ++j) pa += trans[(size_t)j * 4 + q];
            pos[(size_t)nid * 3 + q] += pa / fmaxf((float)(e2 - s), 1.0f);
        }
    }
    const int ndA = n0 + lr, ndB = n0 + 16 + lr;
    char* browA = s_x[0] + lr * 512;
    char* browB = s_x[1] + lr * 512;
    const int sw = (lr & 7) << 4;

    f32x4 aA[8], aB[8];
    #pragma unroll
    for (int mf = 0; mf < 8; ++mf) { aA[mf] = (f32x4){0,0,0,0}; aB[mf] = (f32x4){0,0,0,0}; }
    for (int ks = 0; ks < 8; ++ks) {
        s16x8 bA = *(const s16x8*)(browA + ((ks * 64 + kg * 16) ^ sw));
        s16x8 bB = *(const s16x8*)(browB + ((ks * 64 + kg * 16) ^ sw));
        #pragma unroll
        for (int mf = 0; mf < 8; ++mf) {
            s16x8 a = *(const s16x8*)(nw1t + (size_t)(mf * 16 + lr) * 256 + ks * 32 + kg * 8);
            aA[mf] = __builtin_amdgcn_mfma_f32_16x16x32_bf16(a, bA, aA[mf], 0, 0, 0);
            aB[mf] = __builtin_amdgcn_mfma_f32_16x16x32_bf16(a, bB, aB[mf], 0, 0, 0);
        }
    }
    #pragma unroll
    for (int t = 0; t < 2; ++t) {
        f32x4* acc = t ? aB : aA;
        char* brow = t ? browB : browA;
        #pragma unroll
        for (int mf = 0; mf < 8; ++mf) {
            f32x4 bb = *(const f32x4*)(nb1 + mf * 16 + kg * 4);
            float v0 = silu_f(acc[mf][0] + bb[0]);
            float v1 = silu_f(acc[mf][1] + bb[1]);
            float v2 = silu_f(acc[mf][2] + bb[2]);
            float v3 = silu_f(acc[mf][3] + bb[3]);
            *(uint2*)(brow + ((mf * 32 + kg * 8) ^ sw)) = make_uint2(pk2(v0, v1), pk2(v2, v3));
        }
    }
    #pragma unroll
    for (int mf = 0; mf < 8; ++mf) { aA[mf] = (f32x4){0,0,0,0}; aB[mf] = (f32x4){0,0,0,0}; }
    for (int ks = 0; ks < 4; ++ks) {
        s16x8 bA = *(const s16x8*)(browA + ((ks * 64 + kg * 16) ^ sw));
        s16x8 bB = *(const s16x8*)(browB + ((ks * 64 + kg * 16) ^ sw));
        #pragma unroll
        for (int mf = 0; mf < 8; ++mf) {
            s16x8 a = *(const s16x8*)(nw2t + (size_t)(mf * 16 + lr) * 128 + ks * 32 + kg * 8);
            aA[mf] = __builtin_amdgcn_mfma_f32_16x16x32_bf16(a, bA, aA[mf], 0, 0, 0);
            aB[mf] = __builtin_amdgcn_mfma_f32_16x16x32_bf16(a, bB, aB[mf], 0, 0, 0);
        }
    }
    #pragma unroll
    for (int t = 0; t < 2; ++t) {
        const int nd = t ? ndB : ndA;
        f32x4* acc = t ? aB : aA;
        char* brow = t ? browB : browA;
        if (nd < N) {
            #pragma unroll
            for (int mf = 0; mf < 8; ++mf) {
                f32x4 bb = *(const f32x4*)(nb2 + mf * 16 + kg * 4);
                float* hp = h + (size_t)nd * HD + mf * 16 + kg * 4;
                f32x4 hv = *(const f32x4*)hp;
                hv[0] += acc[mf][0] + bb[0];
                hv[1] += acc[mf][1] + bb[1];
                hv[2] += acc[mf][2] + bb[2];
                hv[3] += acc[mf][3] + bb[3];
                *(f32x4*)hp = hv;
                *(uint2*)(brow + ((mf * 32 + kg * 8) ^ sw)) =
                    make_uint2(pk2(hv[0], hv[1]), pk2(hv[2], hv[3]));
            }
        }
    }
    if (!has_next) return;
    #pragma unroll
    for (int t = 0; t < 2; ++t) {
        const int nd = t ? ndB : ndA;
        const char* brow = t ? browB : browA;
        f32x4 acc2[16];
        #pragma unroll
        for (int mf = 0; mf < 16; ++mf) acc2[mf] = (f32x4){0.f, 0.f, 0.f, 0.f};
        for (int ks = 0; ks < 4; ++ks) {
            s16x8 b = *(const s16x8*)(brow + ((ks * 64 + kg * 16) ^ sw));
            #pragma unroll
            for (int mf = 0; mf < 16; ++mf) {
                s16x8 a = *(const s16x8*)(w1nc_next + (size_t)(mf * 16 + lr) * 128 + ks * 32 + kg * 8);
                acc2[mf] = __builtin_amdgcn_mfma_f32_16x16x32_bf16(a, b, acc2[mf], 0, 0, 0);
            }
        }
        if (nd < N) {
            #pragma unroll
            for (int mf = 0; mf < 16; ++mf) {
                float b0 = 0.f, b1v = 0.f, b2v = 0.f, b3v = 0.f;
                if (mf < 8) {
                    f32x4 bb = *(const f32x4*)(b1_next + mf * 16 + kg * 4);
                    b0 = bb[0]; b1v = bb[1]; b2v = bb[2]; b3v = bb[3];
                }
                int pos2 = ((mf >> 3) << 7) + kg * 32 + (mf & 7) * 4;
                *(uint2*)(apre + (size_t)nd * 256 + pos2) =
                    make_uint2(pk2(acc2[mf][0] + b0, acc2[mf][1] + b1v), pk2(acc2[mf][2] + b2v, acc2[mf][3] + b3v));
            }
        }
    }
}

// ================= h @ emb_out + b via MFMA; batch-segmented coalesced segment_max =================
__global__ __launch_bounds__(64) void embout_mfma_kernel(
    const float* __restrict__ h, const unsigned short* __restrict__ wot,
    const float* __restrict__ b, const int* __restrict__ batch,
    unsigned* __restrict__ g_enc, int N)
{
    __shared__ __align__(16) char s_h[16 * 256];
    __shared__ __align__(16) float s_out[16 * 128];
    const int lane = threadIdx.x;
    const int lr = lane & 15, kg = lane >> 4;
    const int n0 = blockIdx.x * 16;
    {
        int n16 = lane >> 2, q = lane & 3;
        int nn = min(n0 + n16, N - 1);
        int sw2 = (n16 & 7) << 4;
        char* row = s_h + n16 * 256;
        #pragma unroll
        for (int it = 0; it < 8; ++it) {
            int c2 = q * 32 + it * 4;
            float4 v = ld4(h + (size_t)nn * HD + c2);
            *(uint2*)(row + ((c2 * 2) ^ sw2)) = make_uint2(pk2(v.x, v.y), pk2(v.z, v.w));
        }
    }
    const char* brow = s_h + lr * 256;
    const int sw = (lr & 7) << 4;
    f32x4 acc[8];
    #pragma unroll
    for (int mf = 0; mf < 8; ++mf) acc[mf] = (f32x4){0.f, 0.f, 0.f, 0.f};
    for (int ks = 0; ks < 4; ++ks) {
        s16x8 bv = *(const s16x8*)(brow + ((ks * 64 + kg * 16) ^ sw));
        #pragma unroll
        for (int mf = 0; mf < 8; ++mf) {
            s16x8 a = *(const s16x8*)(wot + (size_t)(mf * 16 + lr) * 128 + ks * 32 + kg * 8);
            acc[mf] = __builtin_amdgcn_mfma_f32_16x16x32_bf16(a, bv, acc[mf], 0, 0, 0);
        }
    }
    #pragma unroll
    for (int mf = 0; mf < 8; ++mf) {
        f32x4 bb = *(const f32x4*)(b + mf * 16 + kg * 4);
        f32x4 v = { acc[mf][0] + bb[0], acc[mf][1] + bb[1], acc[mf][2] + bb[2], acc[mf][3] + bb[3] };
        *(f32x4*)(s_out + lr * 128 + mf * 16 + kg * 4) = v;
    }
    const int nmax = min(16, N - n0);
    float m0 = -3.4e38f, m1 = -3.4e38f;
    int cur = batch[n0];
    for (int e = 0; e < nmax; ++e) {
        int bi = batch[n0 + e];
        if (bi != cur) {
            atomicMax(&g_enc[(size_t)cur * HD + lane], enc_max(m0));
            atomicMax(&g_enc[(size_t)cur * HD + 64 + lane], enc_max(m1));
            m0 = -3.4e38f; m1 = -3.4e38f; cur = bi;
        }
        m0 = fmaxf(m0, s_out[e * 128 + lane]);
        m1 = fmaxf(m1, s_out[e * 128 + 64 + lane]);
    }
    atomicMax(&g_enc[(size_t)cur * HD + lane], enc_max(m0));
    atomicMax(&g_enc[(size_t)cur * HD + 64 + lane], enc_max(m1));
}

// ================= decode + 2 ResBlocks =================
__global__ __launch_bounds__(128) void resblock_kernel(
    const unsigned* __restrict__ g_enc,
    const float* __restrict__ rw1, const float* __restrict__ rb1,
    const float* __restrict__ rw2, const float* __restrict__ rb2,
    float* __restrict__ g)
{
    __shared__ float s_g[HD];
    __shared__ float s_t[HD];
    const int b = blockIdx.x, j = threadIdx.x;
    unsigned u = g_enc[(size_t)b * HD + j];
    float v = (u & 0x80000000u) ? __uint_as_float(u & 0x7FFFFFFFu) : __uint_as_float(~u);
    s_g[j] = v;
    __syncthreads();
    for (int r = 0; r < 2; ++r) {
        float a1 = rb1[r * HD + j];
        for (int k = 0; k < HD; ++k) a1 += s_g[k] * rw1[(size_t)r * HD * HD + (size_t)k * HD + j];
        s_t[j] = silu_f(a1);
        __syncthreads();
        float a2 = rb2[r * HD + j];
        for (int k = 0; k < HD; ++k) a2 += s_t[k] * rw2[(size_t)r * HD * HD + (size_t)k * HD + j];
        __syncthreads();
        s_g[j] += a2;
        __syncthreads();
    }
    g[(size_t)b * HD + j] = s_g[j];
}

// ================= head: 8 batch rows per block =================
__global__ __launch_bounds__(256) void head_kernel(
    const float* __restrict__ g, const float* __restrict__ hw, const float* __restrict__ hb,
    float* __restrict__ out, int B)
{
    __shared__ __align__(16) float s_g[HD][8];
    const int b0 = blockIdx.y * 8;
    const int p = blockIdx.x * 256 + threadIdx.x;
    for (int t = threadIdx.x; t < 8 * HD; t += 256) {
        int b = t & 7, k = t >> 3;
        s_g[k][b] = g[(size_t)min(b0 + b, B - 1) * HD + k];
    }
    __syncthreads();
    if (p >= PROP) return;
    float hbp = hb[p];
    float acc[8];
    #pragma unroll
    for (int b = 0; b < 8; ++b) acc[b] = hbp;
    for (int k = 0; k < HD; ++k) {
        float w = hw[(size_t)k * PROP + p];
        float4 g0 = *(const float4*)&s_g[k][0];
        float4 g1 = *(const float4*)&s_g[k][4];
        acc[0] += g0.x * w; acc[1] += g0.y * w; acc[2] += g0.z * w; acc[3] += g0.w * w;
        acc[4] += g1.x * w; acc[5] += g1.y * w; acc[6] += g1.z * w; acc[7] += g1.w * w;
    }
    #pragma unroll
    for (int b = 0; b < 8; ++b)
        if (b0 + b < B) out[(size_t)(b0 + b) * PROP + p] = acc[b];
}

extern "C" void kernel_launch(void* const* d_in, const int* in_sizes, int n_in,
                              void* d_out, int out_size, void* d_ws, size_t ws_size,
                              hipStream_t stream)
{
    const float* x        = (const float*)d_in[0];
    const float* pos_in   = (const float*)d_in[1];
    const float* eattr    = (const float*)d_in[2];
    const int*   ei       = (const int*)d_in[3];
    const int*   batch    = (const int*)d_in[4];
    const float* emb_in_w = (const float*)d_in[5];
    const float* emb_in_b = (const float*)d_in[6];
    const float* emb_out_w= (const float*)d_in[7];
    const float* emb_out_b= (const float*)d_in[8];
    const float* ew1 = (const float*)d_in[9];
    const float* eb1 = (const float*)d_in[10];
    const float* ew2 = (const float*)d_in[11];
    const float* eb2 = (const float*)d_in[12];
    const float* nw1 = (const float*)d_in[13];
    const float* nb1 = (const float*)d_in[14];
    const float* nw2 = (const float*)d_in[15];
    const float* nb2 = (const float*)d_in[16];
    const float* cw1 = (const float*)d_in[17];
    const float* cb1 = (const float*)d_in[18];
    const float* cw2 = (const float*)d_in[19];
    const float* rw1 = (const float*)d_in[20];
    const float* rb1 = (const float*)d_in[21];
    const float* rw2 = (const float*)d_in[22];
    const float* rb2 = (const float*)d_in[23];
    const float* hw  = (const float*)d_in[24];
    const float* hb  = (const float*)d_in[25];
    float* out = (float*)d_out;
    (void)ws_size;

    const int N = in_sizes[0] / 64;     // 20000
    const int E = in_sizes[2] / 16;     // 160000
    const int B = out_size / PROP;      // 1024

    // ---- workspace carve-up ----
    float* wsf = (float*)d_ws;
    float* pos_cur = wsf;   wsf += (size_t)N * 3;
    float* h       = wsf;   wsf += (size_t)N * HD;
    float* g       = wsf;   wsf += (size_t)B * HD;
    float* trans   = wsf;   wsf += (size_t)E * 4;
    wsf += (4 - (((size_t)(wsf - (float*)d_ws)) & 3)) & 3;   // 16B align
    unsigned short* apre  = (unsigned short*)wsf;
    unsigned short* eperm = apre  + (size_t)N * 256;
    unsigned short* w1nc  = eperm + (size_t)E * 16;
    unsigned short* wattr = w1nc  + (size_t)4 * 256 * 128;
    unsigned short* wt2   = wattr + (size_t)4 * 128 * 32;
    unsigned short* cwt1  = wt2   + (size_t)4 * 128 * 128;
    unsigned short* nw1t  = cwt1  + (size_t)4 * 128 * 128;
    unsigned short* nw2t  = nw1t  + (size_t)4 * 128 * 256;
    unsigned short* wembt = nw2t  + (size_t)4 * 128 * 128;
    unsigned short* wot   = wembt + (size_t)128 * 64;
    unsigned short* medge = wot   + (size_t)128 * 128;
    int* ip   = (int*)(medge + (size_t)E * HD);
    unsigned* g_enc = (unsigned*)ip;  ip += (size_t)B * HD;
    int* cnt_i = ip;  ip += N;
    int* rp    = ip;  ip += N + 1;
    int* wp    = ip;  ip += N;
    int* excl  = ip;  ip += N;
    int* bsum  = ip;  ip += 64;
    int* perm  = ip;  ip += E;
    int* rows_s= ip;  ip += E;
    int* cols_s= ip;  ip += E;

    // ---- fused weight prep + g_enc init (one launch) ----
    const int ng = B * HD;
    const int prep_total = 131072 + 16384 + 65536 + 65536 + 131072 + 65536 + 8192 + 16384 + ng;
    prep_all<<<(prep_total + 255) / 256, 256, 0, stream>>>(
        ew1, ew2, cw1, nw1, nw2, emb_in_w, emb_out_w,
        w1nc, wattr, wt2, cwt1, nw1t, nw2t, wembt, wot, g_enc, ng);

    // ---- CSR build (parallel scan) ----
    hipMemsetAsync(cnt_i, 0, (size_t)N * sizeof(int), stream);
    counti_kernel<<<(E + 255) / 256, 256, 0, stream>>>(ei, cnt_i, E);
    const int nb = (N + 1023) / 1024;
    scan_blk<<<nb, 1024, 0, stream>>>(cnt_i, excl, bsum, N);
    scan_top<<<1, 64, 0, stream>>>(bsum, nb);
    scan_add<<<(N + 255) / 256, 256, 0, stream>>>(excl, bsum, rp, wp, N, E);
    scatter_kernel<<<(E + 255) / 256, 256, 0, stream>>>(ei, wp, perm, rows_s, cols_s, E);
    eattr_perm_kernel<<<(E + 255) / 256, 256, 0, stream>>>(eattr, perm, eperm, E);

    hipMemcpyAsync(pos_cur, pos_in, (size_t)N * 3 * sizeof(float),
                   hipMemcpyDeviceToDevice, stream);

    emb_pre_kernel<<<(N + 31) / 32, 128, 0, stream>>>(x, wembt, emb_in_b, w1nc, eb1, h, apre, N);
    const int nblk32 = (N + 31) / 32;   // 625
    for (int l = 0; l < 4; ++l) {
        edge_compute_kernel<<<(E + 63) / 64, 64, 0, stream>>>(
            pos_cur, apre, eperm, rows_s, cols_s,
            wattr + (size_t)l * 128 * 32,
            wt2  + (size_t)l * 128 * 128, eb2 + (size_t)l * HD,
            cwt1 + (size_t)l * 128 * 128, cb1 + (size_t)l * HD,
            cw2 + (size_t)l * HD,
            medge, trans, E);
        node_fused_kernel<<<nblk32, 64, 0, stream>>>(
            h, medge, trans, rp, pos_cur,
            nw1t + (size_t)l * 128 * 256, nb1 + (size_t)l * HD,
            nw2t + (size_t)l * 128 * 128, nb2 + (size_t)l * HD,
            w1nc + (size_t)(l + 1 < 4 ? l + 1 : 0) * 256 * 128,
            eb1 + (size_t)(l + 1 < 4 ? l + 1 : 0) * HD,
            apre, N, l < 3 ? 1 : 0);
    }

    embout_mfma_kernel<<<(N + 15) / 16, 64, 0, stream>>>(h, wot, emb_out_b, batch, g_enc, N);
    resblock_kernel<<<B, 128, 0, stream>>>(g_enc, rw1, rb1, rw2, rb2, g);
    head_kernel<<<dim3((PROP + 255) / 256, (B + 7) / 8), 256, 0, stream>>>(g, hw, hb, out, B);
}

// Round 17
// 551.501 us; speedup vs baseline: 1.3425x; 1.3425x over previous
//
#include <hip/hip_runtime.h>
#include <hip/hip_bf16.h>

#define HD 128
#define PROP 1000

typedef float f32x4 __attribute__((ext_vector_type(4)));
typedef short s16x8 __attribute__((ext_vector_type(8)));

__device__ __forceinline__ float silu_f(float v) { return v / (1.0f + __expf(-v)); }

__device__ __forceinline__ unsigned short f2bf(float f) {
    union { __hip_bfloat16 h; unsigned short u; } v;
    v.h = __float2bfloat16(f);
    return v.u;
}
__device__ __forceinline__ unsigned pk2(float a, float b) {
    union { __hip_bfloat162 h; unsigned u; } v;
    v.h = __float22bfloat162_rn(make_float2(a, b));
    return v.u;
}
__device__ __forceinline__ float bf2f_lo(unsigned u) { return __uint_as_float(u << 16); }
__device__ __forceinline__ float bf2f_hi(unsigned u) { return __uint_as_float(u & 0xffff0000u); }
__device__ __forceinline__ float4 ld4(const float* p) { return *(const float4*)p; }
__device__ __forceinline__ unsigned enc_max(float f) {
    unsigned u = __float_as_uint(f);
    return (u & 0x80000000u) ? ~u : (u | 0x80000000u);
}

// position permutation: m1/apre position p holds feature sigma(p); tau = sigma^-1
// sigma(p) = ((p>>2)&7)*16 + (p>>5)*4 + (p&3)

// ================= CSR build =================
__global__ void counti_kernel(const int* __restrict__ ei, int* __restrict__ cnt, int E) {
    int e = blockIdx.x * 256 + threadIdx.x;
    if (e < E) atomicAdd(&cnt[ei[e]], 1);
}

__global__ __launch_bounds__(1024) void scan_blk(
    const int* __restrict__ cnt, int* __restrict__ excl, int* __restrict__ bsum, int N)
{
    __shared__ int wsum[16], wexc[17];
    const int t = threadIdx.x, lane = t & 63, wid = t >> 6;
    const int gid = blockIdx.x * 1024 + t;
    int v = (gid < N) ? cnt[gid] : 0;
    int incl = v;
    #pragma unroll
    for (int d = 1; d < 64; d <<= 1) {
        int x = __shfl_up(incl, d, 64);
        if (lane >= d) incl += x;
    }
    if (lane == 63) wsum[wid] = incl;
    __syncthreads();
    if (t == 0) {
        int a = 0;
        #pragma unroll
        for (int w2 = 0; w2 < 16; ++w2) { wexc[w2] = a; a += wsum[w2]; }
        wexc[16] = a;
    }
    __syncthreads();
    if (gid < N) excl[gid] = wexc[wid] + incl - v;
    if (t == 0) bsum[blockIdx.x] = wexc[16];
}
__global__ __launch_bounds__(64) void scan_top(int* __restrict__ bsum, int nb) {
    const int lane = threadIdx.x;
    int v = (lane < nb) ? bsum[lane] : 0;
    int incl = v;
    #pragma unroll
    for (int d = 1; d < 64; d <<= 1) {
        int x = __shfl_up(incl, d, 64);
        if (lane >= d) incl += x;
    }
    if (lane < nb) bsum[lane] = incl - v;
}
__global__ void scan_add(const int* __restrict__ excl, const int* __restrict__ bsum,
                         int* __restrict__ rp, int* __restrict__ wp, int N, int E) {
    int gid = blockIdx.x * 256 + threadIdx.x;
    if (gid < N) {
        int r = excl[gid] + bsum[gid >> 10];
        rp[gid] = r; wp[gid] = r;
    }
    if (gid == 0) rp[N] = E;
}

__global__ void scatter_kernel(const int* __restrict__ ei, int* __restrict__ wp,
                               int* __restrict__ perm, int* __restrict__ rows_s,
                               int* __restrict__ cols_s, int E) {
    int e = blockIdx.x * 256 + threadIdx.x;
    if (e < E) {
        int r = ei[e];
        int p = atomicAdd(&wp[r], 1);
        perm[p] = e;
        rows_s[p] = r;
        cols_s[p] = ei[E + e];
    }
}

__global__ void eattr_perm_kernel(const float* __restrict__ eattr, const int* __restrict__ perm,
                                  unsigned short* __restrict__ eperm, int E) {
    int i = blockIdx.x * 256 + threadIdx.x;
    if (i >= E) return;
    const float* src = eattr + (size_t)perm[i] * 16;
    float4 a = ld4(src), b = ld4(src + 4), c = ld4(src + 8), d = ld4(src + 12);
    unsigned short* dst = eperm + (size_t)i * 16;
    *(uint4*)dst       = make_uint4(pk2(a.x, a.y), pk2(a.z, a.w), pk2(b.x, b.y), pk2(b.z, b.w));
    *(uint4*)(dst + 8) = make_uint4(pk2(c.x, c.y), pk2(c.z, c.w), pk2(d.x, d.y), pk2(d.z, d.w));
}

// ================= fused weight prep (single launch; also ginit) =================
__global__ void prep_all(
    const float* __restrict__ ew1, const float* __restrict__ ew2, const float* __restrict__ cw1,
    const float* __restrict__ nw1, const float* __restrict__ nw2,
    const float* __restrict__ emb_in_w, const float* __restrict__ emb_out_w,
    unsigned short* __restrict__ w1nc, unsigned short* __restrict__ wattr,
    unsigned short* __restrict__ wt2, unsigned short* __restrict__ cwt1,
    unsigned short* __restrict__ nw1t, unsigned short* __restrict__ nw2t,
    unsigned short* __restrict__ wembt, unsigned short* __restrict__ wot,
    unsigned* __restrict__ g_enc, int ng)
{
    int idx = blockIdx.x * 256 + threadIdx.x;
    if (idx < 131072) {   // w1nc [4][256][128]
        int k = idx & 127, o2 = (idx >> 7) & 255, l = idx >> 15;
        w1nc[idx] = f2bf(ew1[((size_t)l * 273 + k + ((o2 >> 7) << 7)) * 128 + (o2 & 127)]);
        return;
    }
    idx -= 131072;
    if (idx < 16384) {    // wattr [4][128][32]
        int k = idx & 31, o = (idx >> 5) & 127, l = idx >> 12;
        int ksrc = (k < 16) ? (257 + k) : (k == 16 ? 256 : -1);
        float v = (ksrc >= 0) ? ew1[((size_t)l * 273 + ksrc) * 128 + o] : 0.0f;
        wattr[idx] = f2bf(v);
        return;
    }
    idx -= 16384;
    if (idx < 65536) {    // wt2 sigma-permuted [4][128][128]
        int k = idx & 127, o = (idx >> 7) & 127, l = idx >> 14;
        int ks = ((k >> 2) & 7) * 16 + ((k >> 5) << 2) + (k & 3);
        wt2[idx] = f2bf(ew2[((size_t)l * 128 + ks) * 128 + o]);
        return;
    }
    idx -= 65536;
    if (idx < 65536) {    // cwt1 [4][128][128]
        int k = idx & 127, o = (idx >> 7) & 127, l = idx >> 14;
        cwt1[idx] = f2bf(cw1[((size_t)l * 128 + k) * 128 + o]);
        return;
    }
    idx -= 65536;
    if (idx < 131072) {   // nw1t [4][128][256]
        int k = idx % 256, o = (idx / 256) & 127, l = idx / (256 * 128);
        nw1t[idx] = f2bf(nw1[((size_t)l * 256 + k) * 128 + o]);
        return;
    }
    idx -= 131072;
    if (idx < 65536) {    // nw2t [4][128][128]
        int k = idx & 127, o = (idx >> 7) & 127, l = idx >> 14;
        nw2t[idx] = f2bf(nw2[((size_t)l * 128 + k) * 128 + o]);
        return;
    }
    idx -= 65536;
    if (idx < 8192) {     // wembt [128][64]
        int k = idx & 63, o = idx >> 6;
        wembt[idx] = f2bf(emb_in_w[(size_t)k * 128 + o]);
        return;
    }
    idx -= 8192;
    if (idx < 16384) {    // wot [128][128]
        int k = idx & 127, o = idx >> 7;
        wot[idx] = f2bf(emb_out_w[(size_t)k * 128 + o]);
        return;
    }
    idx -= 16384;
    if (idx < ng) g_enc[idx] = 0x007FFFFFu;
}

// ================= fused emb + layer-0 apre (128 thr = 2 waves x 16 nodes) =================
__global__ __launch_bounds__(128) void emb_pre_kernel(
    const float* __restrict__ x, const unsigned short* __restrict__ wembt,
    const float* __restrict__ bemb,
    const unsigned short* __restrict__ w1nc, const float* __restrict__ b1,
    float* __restrict__ h, unsigned short* __restrict__ apre, int N)
{
    __shared__ __align__(16) char s_xt[32 * 128];
    __shared__ __align__(16) char s_h[32 * 256];
    const int tid = threadIdx.x;
    const int lane = tid & 63, wid = tid >> 6;
    const int lr = lane & 15, kg = lane >> 4;
    const int n0 = blockIdx.x * 32 + wid * 16;
    {
        int n16 = lane >> 2, q = lane & 3;
        int nn = min(n0 + n16, N - 1);
        int sw2 = (n16 & 7) << 4;
        char* row = s_xt + (wid * 16 + n16) * 128;
        #pragma unroll
        for (int it = 0; it < 4; ++it) {
            float4 v = ld4(x + (size_t)nn * 64 + q * 16 + it * 4);
            *(uint2*)(row + ((q * 32 + it * 8) ^ sw2)) = make_uint2(pk2(v.x, v.y), pk2(v.z, v.w));
        }
    }
    const int nd = n0 + lr;
    const int sw = (lr & 7) << 4;
    f32x4 acc[8];
    #pragma unroll
    for (int mf = 0; mf < 8; ++mf) acc[mf] = (f32x4){0.f, 0.f, 0.f, 0.f};
    {
        const char* brow = s_xt + (wid * 16 + lr) * 128;
        for (int ks = 0; ks < 2; ++ks) {
            s16x8 b = *(const s16x8*)(brow + ((ks * 64 + kg * 16) ^ sw));
            #pragma unroll
            for (int mf = 0; mf < 8; ++mf) {
                s16x8 a = *(const s16x8*)(wembt + (size_t)(mf * 16 + lr) * 64 + ks * 32 + kg * 8);
                acc[mf] = __builtin_amdgcn_mfma_f32_16x16x32_bf16(a, b, acc[mf], 0, 0, 0);
            }
        }
    }
    char* hrow = s_h + (wid * 16 + lr) * 256;
    #pragma unroll
    for (int mf = 0; mf < 8; ++mf) {
        f32x4 bb = *(const f32x4*)(bemb + mf * 16 + kg * 4);
        float v0 = acc[mf][0] + bb[0];
        float v1 = acc[mf][1] + bb[1];
        float v2 = acc[mf][2] + bb[2];
        float v3 = acc[mf][3] + bb[3];
        if (nd < N) *(f32x4*)(h + (size_t)nd * HD + mf * 16 + kg * 4) = (f32x4){v0, v1, v2, v3};
        *(uint2*)(hrow + ((mf * 32 + kg * 8) ^ sw)) = make_uint2(pk2(v0, v1), pk2(v2, v3));
    }
    f32x4 acc2[16];
    #pragma unroll
    for (int mf = 0; mf < 16; ++mf) acc2[mf] = (f32x4){0.f, 0.f, 0.f, 0.f};
    for (int ks = 0; ks < 4; ++ks) {
        s16x8 b = *(const s16x8*)(hrow + ((ks * 64 + kg * 16) ^ sw));
        #pragma unroll
        for (int mf = 0; mf < 16; ++mf) {
            s16x8 a = *(const s16x8*)(w1nc + (size_t)(mf * 16 + lr) * 128 + ks * 32 + kg * 8);
            acc2[mf] = __builtin_amdgcn_mfma_f32_16x16x32_bf16(a, b, acc2[mf], 0, 0, 0);
        }
    }
    if (nd < N) {
        #pragma unroll
        for (int mf = 0; mf < 16; ++mf) {
            float b0 = 0.f, b1v = 0.f, b2v = 0.f, b3v = 0.f;
            if (mf < 8) {
                f32x4 bb = *(const f32x4*)(b1 + mf * 16 + kg * 4);
                b0 = bb[0]; b1v = bb[1]; b2v = bb[2]; b3v = bb[3];
            }
            int pos = ((mf >> 3) << 7) + kg * 32 + (mf & 7) * 4;
            *(uint2*)(apre + (size_t)nd * 256 + pos) =
                make_uint2(pk2(acc2[mf][0] + b0, acc2[mf][1] + b1v), pk2(acc2[mf][2] + b2v, acc2[mf][3] + b3v));
        }
    }
}

// ================= edge compute: 1 wave = 32 edges (2 tiles), shared A-frags, direct gathers =================
__global__ __launch_bounds__(64) void edge_compute_kernel(
    const float* __restrict__ pos, const unsigned short* __restrict__ apre,
    const unsigned short* __restrict__ eperm,
    const int* __restrict__ rows_s, const int* __restrict__ cols_s,
    const unsigned short* __restrict__ wattr,
    const unsigned short* __restrict__ wt2, const float* __restrict__ b2,
    const unsigned short* __restrict__ cwt1, const float* __restrict__ cb1,
    const float* __restrict__ cw2,
    unsigned short* __restrict__ medge, float* __restrict__ trans, int E)
{
    __shared__ __align__(16) char s_m[2][16 * 256];

    int wg = blockIdx.x;
    {
        int nper = gridDim.x >> 3;
        if ((gridDim.x & 7) == 0) wg = (wg & 7) * nper + (wg >> 3);
    }
    const int lane = threadIdx.x;
    const int lr = lane & 15, kg = lane >> 4;
    const int i0 = wg * 32;
    const int iA = i0 + lr, iB = i0 + 16 + lr;
    const int icA = min(iA, E - 1), icB = min(iB, E - 1);
    const int rA = rows_s[icA], cA = cols_s[icA];
    const int rB = rows_s[icB], cB = cols_s[icB];

    float dxA = pos[rA*3+0] - pos[cA*3+0];
    float dyA = pos[rA*3+1] - pos[cA*3+1];
    float dzA = pos[rA*3+2] - pos[cA*3+2];
    float dxB = pos[rB*3+0] - pos[cB*3+0];
    float dyB = pos[rB*3+1] - pos[cB*3+1];
    float dzB = pos[rB*3+2] - pos[cB*3+2];
    float radA = dxA*dxA + dyA*dyA + dzA*dzA;
    float radB = dxB*dxB + dyB*dyB + dzB*dzB;

    union { s16x8 v; unsigned u[4]; } battrA, battrB;
    if (kg < 2) {
        battrA.v = *(const s16x8*)(eperm + (size_t)icA * 16 + kg * 8);
        battrB.v = *(const s16x8*)(eperm + (size_t)icB * 16 + kg * 8);
    } else {
        battrA.u[0] = (kg == 2) ? pk2(radA, 0.f) : 0u;
        battrA.u[1] = 0u; battrA.u[2] = 0u; battrA.u[3] = 0u;
        battrB.u[0] = (kg == 2) ? pk2(radB, 0.f) : 0u;
        battrB.u[1] = 0u; battrB.u[2] = 0u; battrB.u[3] = 0u;
    }

    char* mrowA = s_m[0] + lr * 256;
    char* mrowB = s_m[1] + lr * 256;
    const int sw = (lr & 7) << 4;

    f32x4 aA[8], aB[8];
    #pragma unroll
    for (int mf = 0; mf < 8; ++mf) { aA[mf] = (f32x4){0,0,0,0}; aB[mf] = (f32x4){0,0,0,0}; }

    // GEMM1: shared wattr A-frag, MFMA both tiles
    #pragma unroll
    for (int mf = 0; mf < 8; ++mf) {
        s16x8 a = *(const s16x8*)(wattr + (size_t)(mf * 16 + lr) * 32 + kg * 8);
        aA[mf] = __builtin_amdgcn_mfma_f32_16x16x32_bf16(a, battrA.v, aA[mf], 0, 0, 0);
        aB[mf] = __builtin_amdgcn_mfma_f32_16x16x32_bf16(a, battrB.v, aB[mf], 0, 0, 0);
    }
    // epilogue per tile: direct tau gathers (64B runs) + silu, tau store
    #pragma unroll
    for (int t = 0; t < 2; ++t) {
        const int r = t ? rB : rA;
        const int c = t ? cB : cA;
        f32x4* acc = t ? aB : aA;
        char* mrow = t ? mrowB : mrowA;
        uint4 rgq[4], cgq[4];
        {
            const unsigned short* rb = apre + (size_t)r * 256 + kg * 32;
            const unsigned short* cb = apre + (size_t)c * 256 + 128 + kg * 32;
            #pragma unroll
            for (int q = 0; q < 4; ++q) {
                rgq[q] = *(const uint4*)(rb + q * 8);
                cgq[q] = *(const uint4*)(cb + q * 8);
            }
        }
        #pragma unroll
        for (int mf = 0; mf < 8; ++mf) {
            unsigned rlo = ((const unsigned*)&rgq[mf >> 1])[(mf & 1) * 2];
            unsigned rhi = ((const unsigned*)&rgq[mf >> 1])[(mf & 1) * 2 + 1];
            unsigned clo = ((const unsigned*)&cgq[mf >> 1])[(mf & 1) * 2];
            unsigned chi = ((const unsigned*)&cgq[mf >> 1])[(mf & 1) * 2 + 1];
            float v0 = silu_f(acc[mf][0] + bf2f_lo(rlo) + bf2f_lo(clo));
            float v1 = silu_f(acc[mf][1] + bf2f_hi(rlo) + bf2f_hi(clo));
            float v2 = silu_f(acc[mf][2] + bf2f_lo(rhi) + bf2f_lo(chi));
            float v3 = silu_f(acc[mf][3] + bf2f_hi(rhi) + bf2f_hi(chi));
            *(uint2*)(mrow + ((kg * 64 + mf * 8) ^ sw)) = make_uint2(pk2(v0, v1), pk2(v2, v3));
        }
    }

    // GEMM2: shared wt2 A-frags
    #pragma unroll
    for (int mf = 0; mf < 8; ++mf) { aA[mf] = (f32x4){0,0,0,0}; aB[mf] = (f32x4){0,0,0,0}; }
    for (int ks = 0; ks < 4; ++ks) {
        s16x8 bA = *(const s16x8*)(mrowA + ((ks * 64 + kg * 16) ^ sw));
        s16x8 bB = *(const s16x8*)(mrowB + ((ks * 64 + kg * 16) ^ sw));
        #pragma unroll
        for (int mf = 0; mf < 8; ++mf) {
            s16x8 a = *(const s16x8*)(wt2 + (size_t)(mf * 16 + lr) * 128 + ks * 32 + kg * 8);
            aA[mf] = __builtin_amdgcn_mfma_f32_16x16x32_bf16(a, bA, aA[mf], 0, 0, 0);
            aB[mf] = __builtin_amdgcn_mfma_f32_16x16x32_bf16(a, bB, aB[mf], 0, 0, 0);
        }
    }
    #pragma unroll
    for (int t = 0; t < 2; ++t) {
        f32x4* acc = t ? aB : aA;
        char* mrow = t ? mrowB : mrowA;
        #pragma unroll
        for (int mf = 0; mf < 8; ++mf) {
            f32x4 bb = *(const f32x4*)(b2 + mf * 16 + kg * 4);
            float v0 = silu_f(acc[mf][0] + bb[0]);
            float v1 = silu_f(acc[mf][1] + bb[1]);
            float v2 = silu_f(acc[mf][2] + bb[2]);
            float v3 = silu_f(acc[mf][3] + bb[3]);
            *(uint2*)(mrow + ((mf * 32 + kg * 8) ^ sw)) = make_uint2(pk2(v0, v1), pk2(v2, v3));
        }
    }

    // GEMM3: shared cwt1 A-frags
    #pragma unroll
    for (int mf = 0; mf < 8; ++mf) { aA[mf] = (f32x4){0,0,0,0}; aB[mf] = (f32x4){0,0,0,0}; }
    for (int ks = 0; ks < 4; ++ks) {
        s16x8 bA = *(const s16x8*)(mrowA + ((ks * 64 + kg * 16) ^ sw));
        s16x8 bB = *(const s16x8*)(mrowB + ((ks * 64 + kg * 16) ^ sw));
        #pragma unroll
        for (int mf = 0; mf < 8; ++mf) {
            s16x8 a = *(const s16x8*)(cwt1 + (size_t)(mf * 16 + lr) * 128 + ks * 32 + kg * 8);
            aA[mf] = __builtin_amdgcn_mfma_f32_16x16x32_bf16(a, bA, aA[mf], 0, 0, 0);
            aB[mf] = __builtin_amdgcn_mfma_f32_16x16x32_bf16(a, bB, aB[mf], 0, 0, 0);
        }
    }

    // coalesced medge writes for both tiles
    {
        int e = lane >> 2, q = lane & 3;
        int sw2 = (e & 7) << 4;
        #pragma unroll
        for (int t = 0; t < 2; ++t) {
            int ie = i0 + t * 16 + e;
            if (ie < E) {
                const char* src = s_m[t] + e * 256;
                char* dst = (char*)(medge + (size_t)ie * HD);
                #pragma unroll
                for (int it = 0; it < 4; ++it) {
                    uint4 v = *(const uint4*)(src + ((it * 64 + q * 16) ^ sw2));
                    *(uint4*)(dst + it * 64 + q * 16) = v;
                }
            }
        }
    }

    // coord scalars for both tiles
    #pragma unroll
    for (int t = 0; t < 2; ++t) {
        f32x4* acc = t ? aB : aA;
        float part = 0.f;
        #pragma unroll
        for (int mf = 0; mf < 8; ++mf) {
            f32x4 bb = *(const f32x4*)(cb1 + mf * 16 + kg * 4);
            f32x4 cw = *(const f32x4*)(cw2 + mf * 16 + kg * 4);
            part += silu_f(acc[mf][0] + bb[0]) * cw[0];
            part += silu_f(acc[mf][1] + bb[1]) * cw[1];
            part += silu_f(acc[mf][2] + bb[2]) * cw[2];
            part += silu_f(acc[mf][3] + bb[3]) * cw[3];
        }
        part += __shfl_xor(part, 16, 64);
        part += __shfl_xor(part, 32, 64);
        if (kg == 0) {
            int ie = i0 + t * 16 + lr;
            if (ie < E) {
                float dx = t ? dxB : dxA, dy = t ? dyB : dyA, dz = t ? dzB : dzA;
                *(float4*)(trans + (size_t)ie * 4) = make_float4(dx * part, dy * part, dz * part, 0.f);
            }
        }
    }
}

// ================= node model: 1 wave = 32 nodes (2 tiles), shared A-frags =================
__global__ __launch_bounds__(64) void node_fused_kernel(
    float* __restrict__ h, const unsigned short* __restrict__ medge,
    const float* __restrict__ trans, const int* __restrict__ rp,
    float* __restrict__ pos,
    const unsigned short* __restrict__ nw1t, const float* __restrict__ nb1,
    const unsigned short* __restrict__ nw2t, const float* __restrict__ nb2,
    const unsigned short* __restrict__ w1nc_next, const float* __restrict__ b1_next,
    unsigned short* __restrict__ apre, int N, int has_next)
{
    __shared__ __align__(16) char s_x[2][16 * 512];
    const int lane = threadIdx.x;
    const int lr = lane & 15, kg = lane >> 4;
    const int n0 = blockIdx.x * 32;
    #pragma unroll
    for (int t = 0; t < 2; ++t) {
        int n16 = lane >> 2, q = lane & 3;
        int nid = n0 + t * 16 + n16;
        int nn = min(nid, N - 1);
        int sw2 = (n16 & 7) << 4;
        char* row = s_x[t] + n16 * 512;
        #pragma unroll
        for (int it = 0; it < 8; ++it) {
            int c2 = q * 32 + it * 4;
            float4 v = ld4(h + (size_t)nn * HD + c2);
            *(uint2*)(row + ((c2 * 2) ^ sw2)) = make_uint2(pk2(v.x, v.y), pk2(v.z, v.w));
        }
        const int s = rp[nn], e2 = rp[nn + 1];
        float a[32];
        #pragma unroll
        for (int u = 0; u < 32; ++u) a[u] = 0.f;
        for (int j = s; j < e2; ++j) {
            const unsigned short* mp = medge + (size_t)j * HD + q * 32;
            #pragma unroll
            for (int v4 = 0; v4 < 4; ++v4) {
                uint4 w = *(const uint4*)(mp + v4 * 8);
                a[v4*8+0] += bf2f_lo(w.x); a[v4*8+1] += bf2f_hi(w.x);
                a[v4*8+2] += bf2f_lo(w.y); a[v4*8+3] += bf2f_hi(w.y);
                a[v4*8+4] += bf2f_lo(w.z); a[v4*8+5] += bf2f_hi(w.z);
                a[v4*8+6] += bf2f_lo(w.w); a[v4*8+7] += bf2f_hi(w.w);
            }
        }
        #pragma unroll
        for (int it2 = 0; it2 < 4; ++it2) {
            uint4 w = make_uint4(pk2(a[it2*8+0], a[it2*8+1]), pk2(a[it2*8+2], a[it2*8+3]),
                                 pk2(a[it2*8+4], a[it2*8+5]), pk2(a[it2*8+6], a[it2*8+7]));
            *(uint4*)(row + ((256 + q * 64 + it2 * 16) ^ sw2)) = w;
        }
        if (q < 3 && nid < N) {
            float pa = 0.f;
            for (int j = s; j < e2; ++j) pa += trans[(size_t)j * 4 + q];
            pos[(size_t)nid * 3 + q] += pa / fmaxf((float)(e2 - s), 1.0f);
        }
    }
    const int ndA = n0 + lr, ndB = n0 + 16 + lr;
    char* browA = s_x[0] + lr * 512;
    char* browB = s_x[1] + lr * 512;
    const int sw = (lr & 7) << 4;

    f32x4 aA[8], aB[8];
    #pragma unroll
    for (int mf = 0; mf < 8; ++mf) { aA[mf] = (f32x4){0,0,0,0}; aB[mf] = (f32x4){0,0,0,0}; }
    for (int ks = 0; ks < 8; ++ks) {
        s16x8 bA = *(const s16x8*)(browA + ((ks * 64 + kg * 16) ^ sw));
        s16x8 bB = *(const s16x8*)(browB + ((ks * 64 + kg * 16) ^ sw));
        #pragma unroll
        for (int mf = 0; mf < 8; ++mf) {
            s16x8 a = *(const s16x8*)(nw1t + (size_t)(mf * 16 + lr) * 256 + ks * 32 + kg * 8);
            aA[mf] = __builtin_amdgcn_mfma_f32_16x16x32_bf16(a, bA, aA[mf], 0, 0, 0);
            aB[mf] = __builtin_amdgcn_mfma_f32_16x16x32_bf16(a, bB, aB[mf], 0, 0, 0);
        }
    }
    #pragma unroll
    for (int t = 0; t < 2; ++t) {
        f32x4* acc = t ? aB : aA;
        char* brow = t ? browB : browA;
        #pragma unroll
        for (int mf = 0; mf < 8; ++mf) {
            f32x4 bb = *(const f32x4*)(nb1 + mf * 16 + kg * 4);
            float v0 = silu_f(acc[mf][0] + bb[0]);
            float v1 = silu_f(acc[mf][1] + bb[1]);
            float v2 = silu_f(acc[mf][2] + bb[2]);
            float v3 = silu_f(acc[mf][3] + bb[3]);
            *(uint2*)(brow + ((mf * 32 + kg * 8) ^ sw)) = make_uint2(pk2(v0, v1), pk2(v2, v3));
        }
    }
    #pragma unroll
    for (int mf = 0; mf < 8; ++mf) { aA[mf] = (f32x4){0,0,0,0}; aB[mf] = (f32x4){0,0,0,0}; }
    for (int ks = 0; ks < 4; ++ks) {
        s16x8 bA = *(const s16x8*)(browA + ((ks * 64 + kg * 16) ^ sw));
        s16x8 bB = *(const s16x8*)(browB + ((ks * 64 + kg * 16) ^ sw));
        #pragma unroll
        for (int mf = 0; mf < 8; ++mf) {
            s16x8 a = *(const s16x8*)(nw2t + (size_t)(mf * 16 + lr) * 128 + ks * 32 + kg * 8);
            aA[mf] = __builtin_amdgcn_mfma_f32_16x16x32_bf16(a, bA, aA[mf], 0, 0, 0);
            aB[mf] = __builtin_amdgcn_mfma_f32_16x16x32_bf16(a, bB, aB[mf], 0, 0, 0);
        }
    }
    #pragma unroll
    for (int t = 0; t < 2; ++t) {
        const int nd = t ? ndB : ndA;
        f32x4* acc = t ? aB : aA;
        char* brow = t ? browB : browA;
        if (nd < N) {
            #pragma unroll
            for (int mf = 0; mf < 8; ++mf) {
                f32x4 bb = *(const f32x4*)(nb2 + mf * 16 + kg * 4);
                float* hp = h + (size_t)nd * HD + mf * 16 + kg * 4;
                f32x4 hv = *(const f32x4*)hp;
                hv[0] += acc[mf][0] + bb[0];
                hv[1] += acc[mf][1] + bb[1];
                hv[2] += acc[mf][2] + bb[2];
                hv[3] += acc[mf][3] + bb[3];
                *(f32x4*)hp = hv;
                *(uint2*)(brow + ((mf * 32 + kg * 8) ^ sw)) =
                    make_uint2(pk2(hv[0], hv[1]), pk2(hv[2], hv[3]));
            }
        }
    }
    if (!has_next) return;
    #pragma unroll
    for (int t = 0; t < 2; ++t) {
        const int nd = t ? ndB : ndA;
        const char* brow = t ? browB : browA;
        f32x4 acc2[16];
        #pragma unroll
        for (int mf = 0; mf < 16; ++mf) acc2[mf] = (f32x4){0.f, 0.f, 0.f, 0.f};
        for (int ks = 0; ks < 4; ++ks) {
            s16x8 b = *(const s16x8*)(brow + ((ks * 64 + kg * 16) ^ sw));
            #pragma unroll
            for (int mf = 0; mf < 16; ++mf) {
                s16x8 a = *(const s16x8*)(w1nc_next + (size_t)(mf * 16 + lr) * 128 + ks * 32 + kg * 8);
                acc2[mf] = __builtin_amdgcn_mfma_f32_16x16x32_bf16(a, b, acc2[mf], 0, 0, 0);
            }
        }
        if (nd < N) {
            #pragma unroll
            for (int mf = 0; mf < 16; ++mf) {
                float b0 = 0.f, b1v = 0.f, b2v = 0.f, b3v = 0.f;
                if (mf < 8) {
                    f32x4 bb = *(const f32x4*)(b1_next + mf * 16 + kg * 4);
                    b0 = bb[0]; b1v = bb[1]; b2v = bb[2]; b3v = bb[3];
                }
                int pos2 = ((mf >> 3) << 7) + kg * 32 + (mf & 7) * 4;
                *(uint2*)(apre + (size_t)nd * 256 + pos2) =
                    make_uint2(pk2(acc2[mf][0] + b0, acc2[mf][1] + b1v), pk2(acc2[mf][2] + b2v, acc2[mf][3] + b3v));
            }
        }
    }
}

// ================= h @ emb_out + b via MFMA; batch-segmented coalesced segment_max =================
__global__ __launch_bounds__(64) void embout_mfma_kernel(
    const float* __restrict__ h, const unsigned short* __restrict__ wot,
    const float* __restrict__ b, const int* __restrict__ batch,
    unsigned* __restrict__ g_enc, int N)
{
    __shared__ __align__(16) char s_h[16 * 256];
    __shared__ __align__(16) float s_out[16 * 128];
    const int lane = threadIdx.x;
    const int lr = lane & 15, kg = lane >> 4;
    const int n0 = blockIdx.x * 16;
    {
        int n16 = lane >> 2, q = lane & 3;
        int nn = min(n0 + n16, N - 1);
        int sw2 = (n16 & 7) << 4;
        char* row = s_h + n16 * 256;
        #pragma unroll
        for (int it = 0; it < 8; ++it) {
            int c2 = q * 32 + it * 4;
            float4 v = ld4(h + (size_t)nn * HD + c2);
            *(uint2*)(row + ((c2 * 2) ^ sw2)) = make_uint2(pk2(v.x, v.y), pk2(v.z, v.w));
        }
    }
    const char* brow = s_h + lr * 256;
    const int sw = (lr & 7) << 4;
    f32x4 acc[8];
    #pragma unroll
    for (int mf = 0; mf < 8; ++mf) acc[mf] = (f32x4){0.f, 0.f, 0.f, 0.f};
    for (int ks = 0; ks < 4; ++ks) {
        s16x8 bv = *(const s16x8*)(brow + ((ks * 64 + kg * 16) ^ sw));
        #pragma unroll
        for (int mf = 0; mf < 8; ++mf) {
            s16x8 a = *(const s16x8*)(wot + (size_t)(mf * 16 + lr) * 128 + ks * 32 + kg * 8);
            acc[mf] = __builtin_amdgcn_mfma_f32_16x16x32_bf16(a, bv, acc[mf], 0, 0, 0);
        }
    }
    #pragma unroll
    for (int mf = 0; mf < 8; ++mf) {
        f32x4 bb = *(const f32x4*)(b + mf * 16 + kg * 4);
        f32x4 v = { acc[mf][0] + bb[0], acc[mf][1] + bb[1], acc[mf][2] + bb[2], acc[mf][3] + bb[3] };
        *(f32x4*)(s_out + lr * 128 + mf * 16 + kg * 4) = v;
    }
    const int nmax = min(16, N - n0);
    float m0 = -3.4e38f, m1 = -3.4e38f;
    int cur = batch[n0];
    for (int e = 0; e < nmax; ++e) {
        int bi = batch[n0 + e];
        if (bi != cur) {
            atomicMax(&g_enc[(size_t)cur * HD + lane], enc_max(m0));
            atomicMax(&g_enc[(size_t)cur * HD + 64 + lane], enc_max(m1));
            m0 = -3.4e38f; m1 = -3.4e38f; cur = bi;
        }
        m0 = fmaxf(m0, s_out[e * 128 + lane]);
        m1 = fmaxf(m1, s_out[e * 128 + 64 + lane]);
    }
    atomicMax(&g_enc[(size_t)cur * HD + lane], enc_max(m0));
    atomicMax(&g_enc[(size_t)cur * HD + 64 + lane], enc_max(m1));
}

// ================= decode + 2 ResBlocks =================
__global__ __launch_bounds__(128) void resblock_kernel(
    const unsigned* __restrict__ g_enc,
    const float* __restrict__ rw1, const float* __restrict__ rb1,
    const float* __restrict__ rw2, const float* __restrict__ rb2,
    float* __restrict__ g)
{
    __shared__ float s_g[HD];
    __shared__ float s_t[HD];
    const int b = blockIdx.x, j = threadIdx.x;
    unsigned u = g_enc[(size_t)b * HD + j];
    float v = (u & 0x80000000u) ? __uint_as_float(u & 0x7FFFFFFFu) : __uint_as_float(~u);
    s_g[j] = v;
    __syncthreads();
    for (int r = 0; r < 2; ++r) {
        float a1 = rb1[r * HD + j];
        for (int k = 0; k < HD; ++k) a1 += s_g[k] * rw1[(size_t)r * HD * HD + (size_t)k * HD + j];
        s_t[j] = silu_f(a1);
        __syncthreads();
        float a2 = rb2[r * HD + j];
        for (int k = 0; k < HD; ++k) a2 += s_t[k] * rw2[(size_t)r * HD * HD + (size_t)k * HD + j];
        __syncthreads();
        s_g[j] += a2;
        __syncthreads();
    }
    g[(size_t)b * HD + j] = s_g[j];
}

// ================= head: 8 batch rows per block =================
__global__ __launch_bounds__(256) void head_kernel(
    const float* __restrict__ g, const float* __restrict__ hw, const float* __restrict__ hb,
    float* __restrict__ out, int B)
{
    __shared__ __align__(16) float s_g[HD][8];
    const int b0 = blockIdx.y * 8;
    const int p = blockIdx.x * 256 + threadIdx.x;
    for (int t = threadIdx.x; t < 8 * HD; t += 256) {
        int b = t & 7, k = t >> 3;
        s_g[k][b] = g[(size_t)min(b0 + b, B - 1) * HD + k];
    }
    __syncthreads();
    if (p >= PROP) return;
    float hbp = hb[p];
    float acc[8];
    #pragma unroll
    for (int b = 0; b < 8; ++b) acc[b] = hbp;
    for (int k = 0; k < HD; ++k) {
        float w = hw[(size_t)k * PROP + p];
        float4 g0 = *(const float4*)&s_g[k][0];
        float4 g1 = *(const float4*)&s_g[k][4];
        acc[0] += g0.x * w; acc[1] += g0.y * w; acc[2] += g0.z * w; acc[3] += g0.w * w;
        acc[4] += g1.x * w; acc[5] += g1.y * w; acc[6] += g1.z * w; acc[7] += g1.w * w;
    }
    #pragma unroll
    for (int b = 0; b < 8; ++b)
        if (b0 + b < B) out[(size_t)(b0 + b) * PROP + p] = acc[b];
}

extern "C" void kernel_launch(void* const* d_in, const int* in_sizes, int n_in,
                              void* d_out, int out_size, void* d_ws, size_t ws_size,
                              hipStream_t stream)
{
    const float* x        = (const float*)d_in[0];
    const float* pos_in   = (const float*)d_in[1];
    const float* eattr    = (const float*)d_in[2];
    const int*   ei       = (const int*)d_in[3];
    const int*   batch    = (const int*)d_in[4];
    const float* emb_in_w = (const float*)d_in[5];
    const float* emb_in_b = (const float*)d_in[6];
    const float* emb_out_w= (const float*)d_in[7];
    const float* emb_out_b= (const float*)d_in[8];
    const float* ew1 = (const float*)d_in[9];
    const float* eb1 = (const float*)d_in[10];
    const float* ew2 = (const float*)d_in[11];
    const float* eb2 = (const float*)d_in[12];
    const float* nw1 = (const float*)d_in[13];
    const float* nb1 = (const float*)d_in[14];
    const float* nw2 = (const float*)d_in[15];
    const float* nb2 = (const float*)d_in[16];
    const float* cw1 = (const float*)d_in[17];
    const float* cb1 = (const float*)d_in[18];
    const float* cw2 = (const float*)d_in[19];
    const float* rw1 = (const float*)d_in[20];
    const float* rb1 = (const float*)d_in[21];
    const float* rw2 = (const float*)d_in[22];
    const float* rb2 = (const float*)d_in[23];
    const float* hw  = (const float*)d_in[24];
    const float* hb  = (const float*)d_in[25];
    float* out = (float*)d_out;
    (void)ws_size;

    const int N = in_sizes[0] / 64;     // 20000
    const int E = in_sizes[2] / 16;     // 160000
    const int B = out_size / PROP;      // 1024

    // ---- workspace carve-up ----
    float* wsf = (float*)d_ws;
    float* pos_cur = wsf;   wsf += (size_t)N * 3;
    float* h       = wsf;   wsf += (size_t)N * HD;
    float* g       = wsf;   wsf += (size_t)B * HD;
    float* trans   = wsf;   wsf += (size_t)E * 4;
    wsf += (4 - (((size_t)(wsf - (float*)d_ws)) & 3)) & 3;   // 16B align
    unsigned short* apre  = (unsigned short*)wsf;
    unsigned short* eperm = apre  + (size_t)N * 256;
    unsigned short* w1nc  = eperm + (size_t)E * 16;
    unsigned short* wattr = w1nc  + (size_t)4 * 256 * 128;
    unsigned short* wt2   = wattr + (size_t)4 * 128 * 32;
    unsigned short* cwt1  = wt2   + (size_t)4 * 128 * 128;
    unsigned short* nw1t  = cwt1  + (size_t)4 * 128 * 128;
    unsigned short* nw2t  = nw1t  + (size_t)4 * 128 * 256;
    unsigned short* wembt = nw2t  + (size_t)4 * 128 * 128;
    unsigned short* wot   = wembt + (size_t)128 * 64;
    unsigned short* medge = wot   + (size_t)128 * 128;
    int* ip   = (int*)(medge + (size_t)E * HD);
    unsigned* g_enc = (unsigned*)ip;  ip += (size_t)B * HD;
    int* cnt_i = ip;  ip += N;
    int* rp    = ip;  ip += N + 1;
    int* wp    = ip;  ip += N;
    int* excl  = ip;  ip += N;
    int* bsum  = ip;  ip += 64;
    int* perm  = ip;  ip += E;
    int* rows_s= ip;  ip += E;
    int* cols_s= ip;  ip += E;

    // ---- fused weight prep + g_enc init (one launch) ----
    const int ng = B * HD;
    const int prep_total = 131072 + 16384 + 65536 + 65536 + 131072 + 65536 + 8192 + 16384 + ng;
    prep_all<<<(prep_total + 255) / 256, 256, 0, stream>>>(
        ew1, ew2, cw1, nw1, nw2, emb_in_w, emb_out_w,
        w1nc, wattr, wt2, cwt1, nw1t, nw2t, wembt, wot, g_enc, ng);

    // ---- CSR build (parallel scan) ----
    hipMemsetAsync(cnt_i, 0, (size_t)N * sizeof(int), stream);
    counti_kernel<<<(E + 255) / 256, 256, 0, stream>>>(ei, cnt_i, E);
    const int nb = (N + 1023) / 1024;
    scan_blk<<<nb, 1024, 0, stream>>>(cnt_i, excl, bsum, N);
    scan_top<<<1, 64, 0, stream>>>(bsum, nb);
    scan_add<<<(N + 255) / 256, 256, 0, stream>>>(excl, bsum, rp, wp, N, E);
    scatter_kernel<<<(E + 255) / 256, 256, 0, stream>>>(ei, wp, perm, rows_s, cols_s, E);
    eattr_perm_kernel<<<(E + 255) / 256, 256, 0, stream>>>(eattr, perm, eperm, E);

    hipMemcpyAsync(pos_cur, pos_in, (size_t)N * 3 * sizeof(float),
                   hipMemcpyDeviceToDevice, stream);

    emb_pre_kernel<<<(N + 31) / 32, 128, 0, stream>>>(x, wembt, emb_in_b, w1nc, eb1, h, apre, N);
    const int nblk32 = (N + 31) / 32;   // 625
    for (int l = 0; l < 4; ++l) {
        edge_compute_kernel<<<(E + 31) / 32, 64, 0, stream>>>(
            pos_cur, apre, eperm, rows_s, cols_s,
            wattr + (size_t)l * 128 * 32,
            wt2  + (size_t)l * 128 * 128, eb2 + (size_t)l * HD,
            cwt1 + (size_t)l * 128 * 128, cb1 + (size_t)l * HD,
            cw2 + (size_t)l * HD,
            medge, trans, E);
        node_fused_kernel<<<nblk32, 64, 0, stream>>>(
            h, medge, trans, rp, pos_cur,
            nw1t + (size_t)l * 128 * 256, nb1 + (size_t)l * HD,
            nw2t + (size_t)l * 128 * 128, nb2 + (size_t)l * HD,
            w1nc + (size_t)(l + 1 < 4 ? l + 1 : 0) * 256 * 128,
            eb1 + (size_t)(l + 1 < 4 ? l + 1 : 0) * HD,
            apre, N, l < 3 ? 1 : 0);
    }

    embout_mfma_kernel<<<(N + 15) / 16, 64, 0, stream>>>(h, wot, emb_out_b, batch, g_enc, N);
    resblock_kernel<<<B, 128, 0, stream>>>(g_enc, rw1, rb1, rw2, rb2, g);
    head_kernel<<<dim3((PROP + 255) / 256, (B + 7) / 8), 256, 0, stream>>>(g, hw, hb, out, B);
}